// Round 5
// baseline (188.833 us; speedup 1.0000x reference)
//
#include <hip/hip_runtime.h>
#include <hip/hip_bf16.h>

#define BATCH 128
#define TSEQ  256
#define NEMBD 384
#define NHEAD 6
#define HDIM  64
#define C3    1152
#define MROWS 32768      // BATCH*TSEQ
#define KGTOT 48         // NEMBD/8
#define NBH   768        // BATCH*NHEAD
#define BHSZ  16384      // TSEQ*HDIM (ushorts per bh per tensor)

#define NW1_CH (C3 * KGTOT)      // 55296 (Wqkv)
#define NW2_CH (NEMBD * KGTOT)   // 18432 (Wproj)
#define WBLOCKS 288              // (NW1_CH+NW2_CH)/256

typedef __attribute__((ext_vector_type(8))) short short8v;
typedef __attribute__((ext_vector_type(4))) float float4v;

// ---------- helpers ----------

__device__ __forceinline__ unsigned short f2bf(float f) {
  __hip_bfloat16 h = __float2bfloat16(f);   // RNE
  unsigned short u;
  __builtin_memcpy(&u, &h, 2);
  return u;
}

// ---------- weight convert (X convert is fused into gemm_qkv) ----------
__device__ __forceinline__ void convB_body(const float* __restrict__ W,
                                           unsigned short* __restrict__ out,
                                           int N, int idx) {
  const int nl  = idx & 127;
  const int kgg = (idx >> 7) % KGTOT;
  const int nb  = idx / (128 * KGTOT);
  const int n = nb * 128 + nl;
  short8v v;
#pragma unroll
  for (int j = 0; j < 8; ++j)
    v[j] = (short)f2bf(W[(size_t)(kgg * 8 + j) * N + n]);
  *reinterpret_cast<short8v*>(out + (size_t)idx * 8) = v;
}

__global__ __launch_bounds__(256)
void convert_w(const float* __restrict__ W1, const float* __restrict__ W2,
               unsigned short* __restrict__ W1T, unsigned short* __restrict__ W2T) {
  const int wi = blockIdx.x * 256 + threadIdx.x;
  if (wi < NW1_CH) convB_body(W1, W1T, C3, wi);
  else             convB_body(W2, W2T, NEMBD, wi - NW1_CH);
}

// ---------- GEMM core (proj): BK=32, ping-pong dbuf, both operands bf16 ----------
// A: [M/128][K/8][128][8] bf16, B: [N/128][K/8][128][8] bf16. 256 thr = 4 waves.
// LDS: A0|B0|A1|B1, 4096 ushorts each (32 KB).

#define GEMM_STAGE(Ab, Bb, kb, ASL, BSL)                                               \
  _Pragma("unroll") for (int r = 0; r < 2; ++r) {                                      \
    const int i = r * 256 + tid;                                                       \
    const size_t goff = ((size_t)((kb) * 4 + (i >> 7)) * 128 + (i & 127)) * 8;         \
    __builtin_amdgcn_global_load_lds(                                                  \
        (const __attribute__((address_space(1))) unsigned int*)((Ab) + goff),          \
        (__attribute__((address_space(3))) unsigned int*)((ASL) + i * 8), 16, 0, 0);   \
    __builtin_amdgcn_global_load_lds(                                                  \
        (const __attribute__((address_space(1))) unsigned int*)((Bb) + goff),          \
        (__attribute__((address_space(3))) unsigned int*)((BSL) + i * 8), 16, 0, 0);   \
  }

#define GEMM_CORE(Ab, Bb)                                                              \
  __shared__ __attribute__((aligned(16))) unsigned short S[16384];                     \
  const int tid  = threadIdx.x;                                                        \
  const int wave = tid >> 6;                                                           \
  const int lane = tid & 63;                                                           \
  const int wm  = (wave & 1) * 64;                                                     \
  const int wn  = (wave >> 1) * 64;                                                    \
  const int l15 = lane & 15;                                                           \
  const int lq  = lane >> 4;                                                           \
  float4v acc[4][4];                                                                   \
  _Pragma("unroll") for (int i = 0; i < 4; ++i)                                        \
    _Pragma("unroll") for (int j = 0; j < 4; ++j)                                      \
      acc[i][j] = (float4v){0.f, 0.f, 0.f, 0.f};                                       \
  GEMM_STAGE(Ab, Bb, 0, S, S + 4096)                                                   \
  for (int kb = 0; kb < KGTOT / 4; ++kb) {                                             \
    const int cur = (kb & 1) * 8192;                                                   \
    const int nxt = 8192 - cur;                                                        \
    __syncthreads();                                                                   \
    if (kb + 1 < KGTOT / 4) {                                                          \
      GEMM_STAGE(Ab, Bb, kb + 1, S + nxt, S + nxt + 4096)                              \
    }                                                                                  \
    short8v af[4], bfr[4];                                                             \
    _Pragma("unroll") for (int mi = 0; mi < 4; ++mi)                                   \
      af[mi] = *reinterpret_cast<const short8v*>(                                      \
          S + cur + (size_t)(lq * 128 + wm + mi * 16 + l15) * 8);                      \
    _Pragma("unroll") for (int ni = 0; ni < 4; ++ni)                                   \
      bfr[ni] = *reinterpret_cast<const short8v*>(                                     \
          S + cur + 4096 + (size_t)(lq * 128 + wn + ni * 16 + l15) * 8);               \
    _Pragma("unroll") for (int mi = 0; mi < 4; ++mi)                                   \
      _Pragma("unroll") for (int ni = 0; ni < 4; ++ni)                                 \
        acc[mi][ni] = __builtin_amdgcn_mfma_f32_16x16x32_bf16(af[mi], bfr[ni],         \
                                                              acc[mi][ni], 0, 0, 0);   \
  }

// ---------- QKV GEMM: A taken directly from fp32 X, cvt fused in staging ----------
// T14 split staging: issue X float4 loads BEFORE compute (latency hidden under
// 16 MFMAs), cvt+ds_write AFTER compute, before the barrier. B via
// global_load_lds. LDS A layout identical to GEMM_CORE ([kg 4][ml 128][8]).
// Epilogue: K,Q LDS-bounce (coalesced 16B stores); V register-direct ushort4.

#define STAGE_A_LOAD(kb, xv)                                                           \
  _Pragma("unroll") for (int p = 0; p < 4; ++p) {                                      \
    const int f4 = p * 256 + tid;                                                      \
    xv[p] = *reinterpret_cast<const float4*>(                                          \
        Xb + (size_t)(f4 >> 3) * NEMBD + (kb) * 32 + (f4 & 7) * 4);                    \
  }

#define STAGE_A_WRITE(xv, ASL)                                                         \
  _Pragma("unroll") for (int p = 0; p < 4; ++p) {                                      \
    const int f4  = p * 256 + tid;                                                     \
    const int row = f4 >> 3;                                                           \
    const int c4  = f4 & 7;                                                            \
    ushort4 u;                                                                         \
    u.x = f2bf(xv[p].x); u.y = f2bf(xv[p].y);                                          \
    u.z = f2bf(xv[p].z); u.w = f2bf(xv[p].w);                                          \
    *reinterpret_cast<ushort4*>((ASL) + ((c4 >> 1) * 128 + row) * 8 + (c4 & 1) * 4) = u; \
  }

#define STAGE_B(Bb, kb, BSL)                                                           \
  _Pragma("unroll") for (int r = 0; r < 2; ++r) {                                      \
    const int i = r * 256 + tid;                                                       \
    const size_t goff = ((size_t)((kb) * 4 + (i >> 7)) * 128 + (i & 127)) * 8;         \
    __builtin_amdgcn_global_load_lds(                                                  \
        (const __attribute__((address_space(1))) unsigned int*)((Bb) + goff),          \
        (__attribute__((address_space(3))) unsigned int*)((BSL) + i * 8), 16, 0, 0);   \
  }

__global__ __launch_bounds__(256)
void gemm_qkv(const float* __restrict__ X,
              const unsigned short* __restrict__ B,
              unsigned short* __restrict__ KQV) {
  const int ord   = blockIdx.x;
  const int xcd   = ord & 7;
  const int g     = ord >> 3;
  const int mtile = xcd * 32 + (g & 31);
  const int ntile = g >> 5;                 // 0..8; 0-2=K, 3-5=Q, 6-8=V
  const float* Xb = X + (size_t)mtile * 128 * NEMBD;
  const unsigned short* Bb = B + (size_t)ntile * (KGTOT * 128 * 8);

  __shared__ __attribute__((aligned(16))) unsigned short S[16384];
  const int tid  = threadIdx.x;
  const int wave = tid >> 6;
  const int lane = tid & 63;
  const int wm  = (wave & 1) * 64;
  const int wn  = (wave >> 1) * 64;
  const int l15 = lane & 15;
  const int lq  = lane >> 4;
  float4v acc[4][4];
#pragma unroll
  for (int i = 0; i < 4; ++i)
#pragma unroll
    for (int j = 0; j < 4; ++j)
      acc[i][j] = (float4v){0.f, 0.f, 0.f, 0.f};

  {
    float4 xv0[4];
    STAGE_A_LOAD(0, xv0)
    STAGE_B(Bb, 0, S + 4096)
    STAGE_A_WRITE(xv0, S)
  }
  for (int kb = 0; kb < KGTOT / 4; ++kb) {
    const int cur = (kb & 1) * 8192;
    const int nxt = 8192 - cur;
    __syncthreads();
    float4 xv[4];
    if (kb + 1 < KGTOT / 4) {
      STAGE_A_LOAD(kb + 1, xv)            // issue loads; no wait yet
      STAGE_B(Bb, kb + 1, S + nxt + 4096)
    }
    short8v af[4], bfr[4];
#pragma unroll
    for (int mi = 0; mi < 4; ++mi)
      af[mi] = *reinterpret_cast<const short8v*>(
          S + cur + (size_t)(lq * 128 + wm + mi * 16 + l15) * 8);
#pragma unroll
    for (int ni = 0; ni < 4; ++ni)
      bfr[ni] = *reinterpret_cast<const short8v*>(
          S + cur + 4096 + (size_t)(lq * 128 + wn + ni * 16 + l15) * 8);
#pragma unroll
    for (int mi = 0; mi < 4; ++mi)
#pragma unroll
      for (int ni = 0; ni < 4; ++ni)
        acc[mi][ni] = __builtin_amdgcn_mfma_f32_16x16x32_bf16(af[mi], bfr[ni],
                                                              acc[mi][ni], 0, 0, 0);
    if (kb + 1 < KGTOT / 4) {
      STAGE_A_WRITE(xv, S + nxt)          // waits on X loads here, post-MFMA
    }
  }

  // ---- epilogue (identical to R3) ----
  // C/D layout: col = lane&15, row = (lane>>4)*4 + reg
  const int colb = ntile * 128 + wn + l15;
  const int rowb = mtile * 128 + wm + lq * 4;
  if (ntile >= 6) {
    unsigned short* Vb = KQV + (size_t)(2 * NBH) * BHSZ;
#pragma unroll
    for (int ni = 0; ni < 4; ++ni) {
      const int rem = colb + ni * 16 - 768;
      const int hh  = rem >> 6;
      const int d   = rem & 63;
#pragma unroll
      for (int mi = 0; mi < 4; ++mi) {
        const int m  = rowb + mi * 16;
        const int bb = m >> 8;
        const int tt = m & 255;
        ushort4 v;
        v.x = f2bf(acc[mi][ni][0]); v.y = f2bf(acc[mi][ni][1]);
        v.z = f2bf(acc[mi][ni][2]); v.w = f2bf(acc[mi][ni][3]);
        *reinterpret_cast<ushort4*>(
            Vb + (size_t)(bb * NHEAD + hh) * BHSZ + (tt >> 3) * 512 + d * 8 + (tt & 7)) = v;
      }
    }
  } else {
    const int type = (ntile >= 3) ? 1 : 0;          // 0=K, 1=Q
    const float sc = type ? 0.051031036307982884f : 1.0f;
    unsigned short* outb = KQV + (size_t)type * NBH * BHSZ;
    const int hp = ntile - type * 3;                // head-pair 0..2
    const int bb = mtile >> 1;                      // batch index
    const int t0 = (mtile & 1) * 128;               // t-offset of this mtile
    __syncthreads();                                // K-loop done; S reusable
#pragma unroll
    for (int ni = 0; ni < 4; ++ni) {
      const int lc = wn + ni * 16 + l15;            // local col 0..127
      const int c8 = lc >> 3;
      const int dl = lc & 7;
#pragma unroll
      for (int mi = 0; mi < 4; ++mi) {
        const int lr0 = wm + lq * 4 + mi * 16;
#pragma unroll
        for (int r = 0; r < 4; ++r)
          S[(size_t)(c8 * 128 + lr0 + r) * 8 + dl] = f2bf(acc[mi][ni][r] * sc);
      }
    }
    __syncthreads();
#pragma unroll
    for (int it = 0; it < 8; ++it) {
      const int f  = it * 2048 + tid * 8;
      const int c8 = f >> 10;
      const int lr = (f >> 3) & 127;
      const int hh = hp * 2 + (c8 >> 3);
      const int dg = c8 & 7;
      *reinterpret_cast<short8v*>(
          outb + (size_t)(bb * NHEAD + hh) * BHSZ + dg * 2048 + (size_t)(t0 + lr) * 8) =
          *reinterpret_cast<const short8v*>(S + f);
    }
  }
}

// ---------- proj GEMM: fp32 output, row-major; LDS-bounce epilogue ----------
__global__ __launch_bounds__(256)
void gemm_proj(const unsigned short* __restrict__ A,
               const unsigned short* __restrict__ B,
               float* __restrict__ C, int N) {
  const int ord   = blockIdx.x;
  const int xcd   = ord & 7;
  const int g     = ord >> 3;
  const int mtile = xcd * 32 + (g & 31);
  const int ntile = g >> 5;                 // 0..2
  const unsigned short* Ab = A + (size_t)mtile * (KGTOT * 128 * 8);
  const unsigned short* Bb = B + (size_t)ntile * (KGTOT * 128 * 8);
  GEMM_CORE(Ab, Bb)
  float* Sf = reinterpret_cast<float*>(S);  // 8192 floats
#pragma unroll
  for (int pass = 0; pass < 2; ++pass) {
    __syncthreads();                        // S free (K-loop done / pass0 read)
    if ((wave & 1) == pass) {               // waves with wm == pass*64
#pragma unroll
      for (int mi = 0; mi < 4; ++mi)
#pragma unroll
        for (int ni = 0; ni < 4; ++ni)
#pragma unroll
          for (int r = 0; r < 4; ++r)
            Sf[(lq * 4 + mi * 16 + r) * 128 + (wn + ni * 16 + l15)] = acc[mi][ni][r];
    }
    __syncthreads();
    const int rowstart = mtile * 128 + pass * 64;
#pragma unroll
    for (int it = 0; it < 8; ++it) {
      const int f  = it * 1024 + tid * 4;
      const int lr = f >> 7;
      const int lc = f & 127;
      *reinterpret_cast<float4*>(&C[(size_t)(rowstart + lr) * N + ntile * 128 + lc]) =
          *reinterpret_cast<const float4*>(&Sf[f]);
    }
  }
}

// ---------- MFMA flash attention, one block per bh (R5 structure) ----------
__global__ __launch_bounds__(256, 3)
void attn_mfma(const unsigned short* __restrict__ KQV,
               unsigned short* __restrict__ Obf) {
  const int bh   = blockIdx.x;
  const int b    = bh / NHEAD;
  const int h    = bh - b * NHEAD;
  const int tid  = threadIdx.x;
  const int wave = tid >> 6;
  const int lane = tid & 63;
  const int l15  = lane & 15;
  const int lq   = lane >> 4;

  __shared__ __attribute__((aligned(16))) unsigned short Kls[16384];   // [dg 8][t 256][8]
  __shared__ __attribute__((aligned(16))) unsigned short Pt[4][1024];  // per-wave [kg 8][q 16][8]

  const unsigned short* Kb = KQV + (size_t)bh * BHSZ;
  const unsigned short* Qb = KQV + (size_t)(NBH + bh) * BHSZ;
  const unsigned short* Vb = KQV + (size_t)(2 * NBH + bh) * BHSZ;

#pragma unroll
  for (int r = 0; r < 8; ++r) {
    const int i = r * 256 + tid;
    __builtin_amdgcn_global_load_lds(
        (const __attribute__((address_space(1))) unsigned int*)(Kb + (size_t)i * 8),
        (__attribute__((address_space(3))) unsigned int*)(Kls + i * 8), 16, 0, 0);
  }
  __syncthreads();   // only barrier in the kernel

  unsigned short* Pw = Pt[wave];

  for (int j = 0; j < 4; ++j) {
    short8v qa[2];
#pragma unroll
    for (int s = 0; s < 2; ++s)
      qa[s] = *reinterpret_cast<const short8v*>(
          Qb + (size_t)(s * 4 + lq) * 2048 + (size_t)(j * 64 + wave * 16 + l15) * 8);

    float4v o[4];
#pragma unroll
    for (int nf = 0; nf < 4; ++nf) o[nf] = (float4v){0.f, 0.f, 0.f, 0.f};
    float4v lp = (float4v){0.f, 0.f, 0.f, 0.f};

    for (int kt = 0; kt <= j; ++kt) {
      short8v vf[2][4];
#pragma unroll
      for (int s = 0; s < 2; ++s)
#pragma unroll
        for (int nf = 0; nf < 4; ++nf)
          vf[s][nf] = *reinterpret_cast<const short8v*>(
              Vb + (size_t)(kt * 8 + s * 4 + lq) * 512 + (size_t)(nf * 16 + l15) * 8);

      float4v sf[4];
#pragma unroll
      for (int nf = 0; nf < 4; ++nf) sf[nf] = (float4v){0.f, 0.f, 0.f, 0.f};
#pragma unroll
      for (int s = 0; s < 2; ++s) {
        short8v kf[4];
#pragma unroll
        for (int nf = 0; nf < 4; ++nf)
          kf[nf] = *reinterpret_cast<const short8v*>(
              Kls + (size_t)(s * 4 + lq) * 2048 + (size_t)(kt * 64 + nf * 16 + l15) * 8);
#pragma unroll
        for (int nf = 0; nf < 4; ++nf)
          sf[nf] = __builtin_amdgcn_mfma_f32_16x16x32_bf16(qa[s], kf[nf], sf[nf], 0, 0, 0);
      }

      if (kt == j) {
        const int qit = wave * 16 + lq * 4;
#pragma unroll
        for (int nf = 0; nf < 4; ++nf) {
          const int key = nf * 16 + l15;
#pragma unroll
          for (int r = 0; r < 4; ++r)
            if (key > qit + r) sf[nf][r] = -INFINITY;
        }
      }

#pragma unroll
      for (int nf = 0; nf < 4; ++nf) {
        const int kg  = nf * 2 + (l15 >> 3);
        const int pos = l15 & 7;
#pragma unroll
        for (int r = 0; r < 4; ++r) {
          const float p = __expf(sf[nf][r]);
          lp[r] += p;
          Pw[(kg * 16 + lq * 4 + r) * 8 + pos] = f2bf(p);
        }
      }

#pragma unroll
      for (int s = 0; s < 2; ++s) {
        short8v pa = *reinterpret_cast<const short8v*>(
            Pw + (size_t)((s * 4 + lq) * 16 + l15) * 8);
#pragma unroll
        for (int nf = 0; nf < 4; ++nf)
          o[nf] = __builtin_amdgcn_mfma_f32_16x16x32_bf16(pa, vf[s][nf], o[nf], 0, 0, 0);
      }
    }

#pragma unroll
    for (int off = 1; off <= 8; off <<= 1)
#pragma unroll
      for (int r = 0; r < 4; ++r)
        lp[r] += __shfl_xor(lp[r], off);
    float4v inv;
#pragma unroll
    for (int r = 0; r < 4; ++r) inv[r] = 1.f / lp[r];

    const int tq = j * 64 + wave * 16 + lq * 4;
#pragma unroll
    for (int nf = 0; nf < 4; ++nf) {
      const int d   = nf * 16 + l15;
      const int gg  = h * 8 + (d >> 3);
      const int pos = d & 7;
#pragma unroll
      for (int r = 0; r < 4; ++r) {
        const int m = b * TSEQ + tq + r;
        Obf[((size_t)(m >> 7) * KGTOT + gg) * 1024 + (size_t)(m & 127) * 8 + pos] =
            f2bf(o[nf][r] * inv[r]);
      }
    }
  }
}

// ---------- launch ----------

extern "C" void kernel_launch(void* const* d_in, const int* in_sizes, int n_in,
                              void* d_out, int out_size, void* d_ws, size_t ws_size,
                              hipStream_t stream) {
  const float* X     = (const float*)d_in[0];   // (128,256,384)
  const float* Wqkv  = (const float*)d_in[1];   // (384,1152)
  const float* Wproj = (const float*)d_in[2];   // (384,384)
  float* out = (float*)d_out;

  // ws layout (bytes):
  //   KQV bf16: K[768][8][256][8] | Q same | V [768][32][64][8] : 75,497,472
  //   Obf (attn output, tiled A layout for proj)                : 25,165,824
  //   WqkvT bf16 tiled                                          :    884,736
  //   WprojT bf16 tiled                                         :    294,912
  unsigned short* KQV    = (unsigned short*)d_ws;
  unsigned short* Obf    = (unsigned short*)((char*)d_ws + 75497472);
  unsigned short* WqkvT  = (unsigned short*)((char*)d_ws + 75497472 + 25165824);
  unsigned short* WprojT = (unsigned short*)((char*)d_ws + 75497472 + 25165824 + 884736);

  dim3 blk(256);
  convert_w<<<dim3(WBLOCKS), blk, 0, stream>>>(Wqkv, Wproj, WqkvT, WprojT);
  gemm_qkv<<<dim3(2304), blk, 0, stream>>>(X, WqkvT, KQV);
  attn_mfma<<<dim3(NBH), blk, 0, stream>>>(KQV, Obf);
  gemm_proj<<<dim3(768), blk, 0, stream>>>(Obf, WprojT, out, NEMBD);
}

// Round 6
// 188.150 us; speedup vs baseline: 1.0036x; 1.0036x over previous
//
#include <hip/hip_runtime.h>
#include <hip/hip_bf16.h>

#define BATCH 128
#define TSEQ  256
#define NEMBD 384
#define NHEAD 6
#define HDIM  64
#define C3    1152
#define MROWS 32768      // BATCH*TSEQ
#define KGTOT 48         // NEMBD/8
#define NBH   768        // BATCH*NHEAD
#define BHSZ  16384      // TSEQ*HDIM (ushorts per bh per tensor)

#define NW1_CH (C3 * KGTOT)      // 55296 (Wqkv)
#define NW2_CH (NEMBD * KGTOT)   // 18432 (Wproj)
#define WBLOCKS 288              // (NW1_CH+NW2_CH)/256

typedef __attribute__((ext_vector_type(8))) short short8v;
typedef __attribute__((ext_vector_type(4))) float float4v;

// ---------- helpers ----------

__device__ __forceinline__ unsigned short f2bf(float f) {
  __hip_bfloat16 h = __float2bfloat16(f);   // RNE
  unsigned short u;
  __builtin_memcpy(&u, &h, 2);
  return u;
}

// ---------- weight convert (X convert is fused into gemm_qkv) ----------
__device__ __forceinline__ void convB_body(const float* __restrict__ W,
                                           unsigned short* __restrict__ out,
                                           int N, int idx) {
  const int nl  = idx & 127;
  const int kgg = (idx >> 7) % KGTOT;
  const int nb  = idx / (128 * KGTOT);
  const int n = nb * 128 + nl;
  short8v v;
#pragma unroll
  for (int j = 0; j < 8; ++j)
    v[j] = (short)f2bf(W[(size_t)(kgg * 8 + j) * N + n]);
  *reinterpret_cast<short8v*>(out + (size_t)idx * 8) = v;
}

__global__ __launch_bounds__(256)
void convert_w(const float* __restrict__ W1, const float* __restrict__ W2,
               unsigned short* __restrict__ W1T, unsigned short* __restrict__ W2T) {
  const int wi = blockIdx.x * 256 + threadIdx.x;
  if (wi < NW1_CH) convB_body(W1, W1T, C3, wi);
  else             convB_body(W2, W2T, NEMBD, wi - NW1_CH);
}

// ---------- GEMM core (proj): BK=32, ping-pong dbuf, both operands bf16 ----------
// A: [M/128][K/8][128][8] bf16, B: [N/128][K/8][128][8] bf16. 256 thr = 4 waves.
// LDS: A0|B0|A1|B1, 4096 ushorts each (32 KB).

#define GEMM_STAGE(Ab, Bb, kb, ASL, BSL)                                               \
  _Pragma("unroll") for (int r = 0; r < 2; ++r) {                                      \
    const int i = r * 256 + tid;                                                       \
    const size_t goff = ((size_t)((kb) * 4 + (i >> 7)) * 128 + (i & 127)) * 8;         \
    __builtin_amdgcn_global_load_lds(                                                  \
        (const __attribute__((address_space(1))) unsigned int*)((Ab) + goff),          \
        (__attribute__((address_space(3))) unsigned int*)((ASL) + i * 8), 16, 0, 0);   \
    __builtin_amdgcn_global_load_lds(                                                  \
        (const __attribute__((address_space(1))) unsigned int*)((Bb) + goff),          \
        (__attribute__((address_space(3))) unsigned int*)((BSL) + i * 8), 16, 0, 0);   \
  }

#define GEMM_CORE(Ab, Bb)                                                              \
  __shared__ __attribute__((aligned(16))) unsigned short S[16384];                     \
  const int tid  = threadIdx.x;                                                        \
  const int wave = tid >> 6;                                                           \
  const int lane = tid & 63;                                                           \
  const int wm  = (wave & 1) * 64;                                                     \
  const int wn  = (wave >> 1) * 64;                                                    \
  const int l15 = lane & 15;                                                           \
  const int lq  = lane >> 4;                                                           \
  float4v acc[4][4];                                                                   \
  _Pragma("unroll") for (int i = 0; i < 4; ++i)                                        \
    _Pragma("unroll") for (int j = 0; j < 4; ++j)                                      \
      acc[i][j] = (float4v){0.f, 0.f, 0.f, 0.f};                                       \
  GEMM_STAGE(Ab, Bb, 0, S, S + 4096)                                                   \
  for (int kb = 0; kb < KGTOT / 4; ++kb) {                                             \
    const int cur = (kb & 1) * 8192;                                                   \
    const int nxt = 8192 - cur;                                                        \
    __syncthreads();                                                                   \
    if (kb + 1 < KGTOT / 4) {                                                          \
      GEMM_STAGE(Ab, Bb, kb + 1, S + nxt, S + nxt + 4096)                              \
    }                                                                                  \
    short8v af[4], bfr[4];                                                             \
    _Pragma("unroll") for (int mi = 0; mi < 4; ++mi)                                   \
      af[mi] = *reinterpret_cast<const short8v*>(                                      \
          S + cur + (size_t)(lq * 128 + wm + mi * 16 + l15) * 8);                      \
    _Pragma("unroll") for (int ni = 0; ni < 4; ++ni)                                   \
      bfr[ni] = *reinterpret_cast<const short8v*>(                                     \
          S + cur + 4096 + (size_t)(lq * 128 + wn + ni * 16 + l15) * 8);               \
    _Pragma("unroll") for (int mi = 0; mi < 4; ++mi)                                   \
      _Pragma("unroll") for (int ni = 0; ni < 4; ++ni)                                 \
        acc[mi][ni] = __builtin_amdgcn_mfma_f32_16x16x32_bf16(af[mi], bfr[ni],         \
                                                              acc[mi][ni], 0, 0, 0);   \
  }

// ---------- QKV GEMM: fused fp32->bf16 A staging, mtile-major grid ----------
// mtile-major: the 9 blocks (ntile 0..8) sharing one 196KB X panel run
// consecutively on one XCD -> live set ~11 panels + all B (884KB) < 4MiB L2,
// X fetched from HBM ~once (R5's ntile-major thrashed: 6.3MB/XCD > L2 ->
// FETCH 143MB).
// Staging: thread owns chunks c = p*256+tid; kg=c&3, r=c>>2. Global: 4 lanes
// cover one row's 32 cols (128B contiguous). LDS: one ds_write_b128 per chunk
// at byte ((kg*128+r)*16)^((kg&1)<<6) -- XOR swizzle makes write and MFMA
// A-read both <=2-way (free, m136). T14 split: loads issued BEFORE the 16
// MFMAs, cvt+ds_write after.
// Epilogue: K,Q LDS-bounce (coalesced 16B stores); V register-direct ushort4.

#define STAGE_A_LOAD(kb, xv)                                                           \
  _Pragma("unroll") for (int p = 0; p < 2; ++p) {                                      \
    const int c  = p * 256 + tid;                                                      \
    const int kg = c & 3;                                                              \
    const int r  = c >> 2;                                                             \
    const float* src = Xb + (size_t)r * NEMBD + (kb) * 32 + kg * 8;                    \
    xv[p][0] = *reinterpret_cast<const float4*>(src);                                  \
    xv[p][1] = *reinterpret_cast<const float4*>(src + 4);                              \
  }

#define STAGE_A_WRITE(xv, baseBytes)                                                   \
  _Pragma("unroll") for (int p = 0; p < 2; ++p) {                                      \
    const int c  = p * 256 + tid;                                                      \
    const int kg = c & 3;                                                              \
    const int r  = c >> 2;                                                             \
    short8v u;                                                                         \
    u[0] = (short)f2bf(xv[p][0].x); u[1] = (short)f2bf(xv[p][0].y);                    \
    u[2] = (short)f2bf(xv[p][0].z); u[3] = (short)f2bf(xv[p][0].w);                    \
    u[4] = (short)f2bf(xv[p][1].x); u[5] = (short)f2bf(xv[p][1].y);                    \
    u[6] = (short)f2bf(xv[p][1].z); u[7] = (short)f2bf(xv[p][1].w);                    \
    const int bo = (((kg) * 128 + r) * 16) ^ ((kg & 1) << 6);                          \
    *reinterpret_cast<short8v*>(Sb + (baseBytes) + bo) = u;                            \
  }

#define STAGE_B(Bb, kb, BSL)                                                           \
  _Pragma("unroll") for (int r = 0; r < 2; ++r) {                                      \
    const int i = r * 256 + tid;                                                       \
    const size_t goff = ((size_t)((kb) * 4 + (i >> 7)) * 128 + (i & 127)) * 8;         \
    __builtin_amdgcn_global_load_lds(                                                  \
        (const __attribute__((address_space(1))) unsigned int*)((Bb) + goff),          \
        (__attribute__((address_space(3))) unsigned int*)((BSL) + i * 8), 16, 0, 0);   \
  }

__global__ __launch_bounds__(256)
void gemm_qkv(const float* __restrict__ X,
              const unsigned short* __restrict__ B,
              unsigned short* __restrict__ KQV) {
  const int ord   = blockIdx.x;
  const int xcd   = ord & 7;
  const int g     = ord >> 3;               // 0..287
  const int mtile = xcd * 32 + g / 9;
  const int ntile = g % 9;                  // 0..8; 0-2=K, 3-5=Q, 6-8=V
  const float* Xb = X + (size_t)mtile * 128 * NEMBD;
  const unsigned short* Bb = B + (size_t)ntile * (KGTOT * 128 * 8);

  __shared__ __attribute__((aligned(16))) unsigned short S[16384];
  char* Sb = reinterpret_cast<char*>(S);
  const int tid  = threadIdx.x;
  const int wave = tid >> 6;
  const int lane = tid & 63;
  const int wm  = (wave & 1) * 64;
  const int wn  = (wave >> 1) * 64;
  const int l15 = lane & 15;
  const int lq  = lane >> 4;
  float4v acc[4][4];
#pragma unroll
  for (int i = 0; i < 4; ++i)
#pragma unroll
    for (int j = 0; j < 4; ++j)
      acc[i][j] = (float4v){0.f, 0.f, 0.f, 0.f};

  {
    float4 xv0[2][2];
    STAGE_A_LOAD(0, xv0)
    STAGE_B(Bb, 0, S + 4096)
    STAGE_A_WRITE(xv0, 0)
  }
  for (int kb = 0; kb < KGTOT / 4; ++kb) {
    const int cur = (kb & 1) * 8192;        // ushort offset of current A buf
    const int nxt = 8192 - cur;
    __syncthreads();
    float4 xv[2][2];
    if (kb + 1 < KGTOT / 4) {
      STAGE_A_LOAD(kb + 1, xv)              // issue loads; no wait yet
      STAGE_B(Bb, kb + 1, S + nxt + 4096)
    }
    short8v af[4], bfr[4];
#pragma unroll
    for (int mi = 0; mi < 4; ++mi) {
      const int row = wm + mi * 16 + l15;
      const int bo  = ((lq * 128 + row) * 16) ^ ((lq & 1) << 6);
      af[mi] = *reinterpret_cast<const short8v*>(Sb + cur * 2 + bo);
    }
#pragma unroll
    for (int ni = 0; ni < 4; ++ni)
      bfr[ni] = *reinterpret_cast<const short8v*>(
          S + cur + 4096 + (size_t)(lq * 128 + wn + ni * 16 + l15) * 8);
#pragma unroll
    for (int mi = 0; mi < 4; ++mi)
#pragma unroll
      for (int ni = 0; ni < 4; ++ni)
        acc[mi][ni] = __builtin_amdgcn_mfma_f32_16x16x32_bf16(af[mi], bfr[ni],
                                                              acc[mi][ni], 0, 0, 0);
    if (kb + 1 < KGTOT / 4) {
      STAGE_A_WRITE(xv, nxt * 2)            // waits on X loads here, post-MFMA
    }
  }

  // ---- epilogue (identical to R3) ----
  // C/D layout: col = lane&15, row = (lane>>4)*4 + reg
  const int colb = ntile * 128 + wn + l15;
  const int rowb = mtile * 128 + wm + lq * 4;
  if (ntile >= 6) {
    unsigned short* Vb = KQV + (size_t)(2 * NBH) * BHSZ;
#pragma unroll
    for (int ni = 0; ni < 4; ++ni) {
      const int rem = colb + ni * 16 - 768;
      const int hh  = rem >> 6;
      const int d   = rem & 63;
#pragma unroll
      for (int mi = 0; mi < 4; ++mi) {
        const int m  = rowb + mi * 16;
        const int bb = m >> 8;
        const int tt = m & 255;
        ushort4 v;
        v.x = f2bf(acc[mi][ni][0]); v.y = f2bf(acc[mi][ni][1]);
        v.z = f2bf(acc[mi][ni][2]); v.w = f2bf(acc[mi][ni][3]);
        *reinterpret_cast<ushort4*>(
            Vb + (size_t)(bb * NHEAD + hh) * BHSZ + (tt >> 3) * 512 + d * 8 + (tt & 7)) = v;
      }
    }
  } else {
    const int type = (ntile >= 3) ? 1 : 0;          // 0=K, 1=Q
    const float sc = type ? 0.051031036307982884f : 1.0f;
    unsigned short* outb = KQV + (size_t)type * NBH * BHSZ;
    const int hp = ntile - type * 3;                // head-pair 0..2
    const int bb = mtile >> 1;                      // batch index
    const int t0 = (mtile & 1) * 128;               // t-offset of this mtile
    __syncthreads();                                // K-loop done; S reusable
#pragma unroll
    for (int ni = 0; ni < 4; ++ni) {
      const int lc = wn + ni * 16 + l15;            // local col 0..127
      const int c8 = lc >> 3;
      const int dl = lc & 7;
#pragma unroll
      for (int mi = 0; mi < 4; ++mi) {
        const int lr0 = wm + lq * 4 + mi * 16;
#pragma unroll
        for (int r = 0; r < 4; ++r)
          S[(size_t)(c8 * 128 + lr0 + r) * 8 + dl] = f2bf(acc[mi][ni][r] * sc);
      }
    }
    __syncthreads();
#pragma unroll
    for (int it = 0; it < 8; ++it) {
      const int f  = it * 2048 + tid * 8;
      const int c8 = f >> 10;
      const int lr = (f >> 3) & 127;
      const int hh = hp * 2 + (c8 >> 3);
      const int dg = c8 & 7;
      *reinterpret_cast<short8v*>(
          outb + (size_t)(bb * NHEAD + hh) * BHSZ + dg * 2048 + (size_t)(t0 + lr) * 8) =
          *reinterpret_cast<const short8v*>(S + f);
    }
  }
}

// ---------- proj GEMM: fp32 output, row-major; LDS-bounce epilogue ----------
__global__ __launch_bounds__(256)
void gemm_proj(const unsigned short* __restrict__ A,
               const unsigned short* __restrict__ B,
               float* __restrict__ C, int N) {
  const int ord   = blockIdx.x;
  const int xcd   = ord & 7;
  const int g     = ord >> 3;
  const int mtile = xcd * 32 + (g & 31);
  const int ntile = g >> 5;                 // 0..2
  const unsigned short* Ab = A + (size_t)mtile * (KGTOT * 128 * 8);
  const unsigned short* Bb = B + (size_t)ntile * (KGTOT * 128 * 8);
  GEMM_CORE(Ab, Bb)
  float* Sf = reinterpret_cast<float*>(S);  // 8192 floats
#pragma unroll
  for (int pass = 0; pass < 2; ++pass) {
    __syncthreads();                        // S free (K-loop done / pass0 read)
    if ((wave & 1) == pass) {               // waves with wm == pass*64
#pragma unroll
      for (int mi = 0; mi < 4; ++mi)
#pragma unroll
        for (int ni = 0; ni < 4; ++ni)
#pragma unroll
          for (int r = 0; r < 4; ++r)
            Sf[(lq * 4 + mi * 16 + r) * 128 + (wn + ni * 16 + l15)] = acc[mi][ni][r];
    }
    __syncthreads();
    const int rowstart = mtile * 128 + pass * 64;
#pragma unroll
    for (int it = 0; it < 8; ++it) {
      const int f  = it * 1024 + tid * 4;
      const int lr = f >> 7;
      const int lc = f & 127;
      *reinterpret_cast<float4*>(&C[(size_t)(rowstart + lr) * N + ntile * 128 + lc]) =
          *reinterpret_cast<const float4*>(&Sf[f]);
    }
  }
}

// ---------- MFMA flash attention, one block per bh (R5 structure) ----------
__global__ __launch_bounds__(256, 3)
void attn_mfma(const unsigned short* __restrict__ KQV,
               unsigned short* __restrict__ Obf) {
  const int bh   = blockIdx.x;
  const int b    = bh / NHEAD;
  const int h    = bh - b * NHEAD;
  const int tid  = threadIdx.x;
  const int wave = tid >> 6;
  const int lane = tid & 63;
  const int l15  = lane & 15;
  const int lq   = lane >> 4;

  __shared__ __attribute__((aligned(16))) unsigned short Kls[16384];   // [dg 8][t 256][8]
  __shared__ __attribute__((aligned(16))) unsigned short Pt[4][1024];  // per-wave [kg 8][q 16][8]

  const unsigned short* Kb = KQV + (size_t)bh * BHSZ;
  const unsigned short* Qb = KQV + (size_t)(NBH + bh) * BHSZ;
  const unsigned short* Vb = KQV + (size_t)(2 * NBH + bh) * BHSZ;

#pragma unroll
  for (int r = 0; r < 8; ++r) {
    const int i = r * 256 + tid;
    __builtin_amdgcn_global_load_lds(
        (const __attribute__((address_space(1))) unsigned int*)(Kb + (size_t)i * 8),
        (__attribute__((address_space(3))) unsigned int*)(Kls + i * 8), 16, 0, 0);
  }
  __syncthreads();   // only barrier in the kernel

  unsigned short* Pw = Pt[wave];

  for (int j = 0; j < 4; ++j) {
    short8v qa[2];
#pragma unroll
    for (int s = 0; s < 2; ++s)
      qa[s] = *reinterpret_cast<const short8v*>(
          Qb + (size_t)(s * 4 + lq) * 2048 + (size_t)(j * 64 + wave * 16 + l15) * 8);

    float4v o[4];
#pragma unroll
    for (int nf = 0; nf < 4; ++nf) o[nf] = (float4v){0.f, 0.f, 0.f, 0.f};
    float4v lp = (float4v){0.f, 0.f, 0.f, 0.f};

    for (int kt = 0; kt <= j; ++kt) {
      short8v vf[2][4];
#pragma unroll
      for (int s = 0; s < 2; ++s)
#pragma unroll
        for (int nf = 0; nf < 4; ++nf)
          vf[s][nf] = *reinterpret_cast<const short8v*>(
              Vb + (size_t)(kt * 8 + s * 4 + lq) * 512 + (size_t)(nf * 16 + l15) * 8);

      float4v sf[4];
#pragma unroll
      for (int nf = 0; nf < 4; ++nf) sf[nf] = (float4v){0.f, 0.f, 0.f, 0.f};
#pragma unroll
      for (int s = 0; s < 2; ++s) {
        short8v kf[4];
#pragma unroll
        for (int nf = 0; nf < 4; ++nf)
          kf[nf] = *reinterpret_cast<const short8v*>(
              Kls + (size_t)(s * 4 + lq) * 2048 + (size_t)(kt * 64 + nf * 16 + l15) * 8);
#pragma unroll
        for (int nf = 0; nf < 4; ++nf)
          sf[nf] = __builtin_amdgcn_mfma_f32_16x16x32_bf16(qa[s], kf[nf], sf[nf], 0, 0, 0);
      }

      if (kt == j) {
        const int qit = wave * 16 + lq * 4;
#pragma unroll
        for (int nf = 0; nf < 4; ++nf) {
          const int key = nf * 16 + l15;
#pragma unroll
          for (int r = 0; r < 4; ++r)
            if (key > qit + r) sf[nf][r] = -INFINITY;
        }
      }

#pragma unroll
      for (int nf = 0; nf < 4; ++nf) {
        const int kg  = nf * 2 + (l15 >> 3);
        const int pos = l15 & 7;
#pragma unroll
        for (int r = 0; r < 4; ++r) {
          const float p = __expf(sf[nf][r]);
          lp[r] += p;
          Pw[(kg * 16 + lq * 4 + r) * 8 + pos] = f2bf(p);
        }
      }

#pragma unroll
      for (int s = 0; s < 2; ++s) {
        short8v pa = *reinterpret_cast<const short8v*>(
            Pw + (size_t)((s * 4 + lq) * 16 + l15) * 8);
#pragma unroll
        for (int nf = 0; nf < 4; ++nf)
          o[nf] = __builtin_amdgcn_mfma_f32_16x16x32_bf16(pa, vf[s][nf], o[nf], 0, 0, 0);
      }
    }

#pragma unroll
    for (int off = 1; off <= 8; off <<= 1)
#pragma unroll
      for (int r = 0; r < 4; ++r)
        lp[r] += __shfl_xor(lp[r], off);
    float4v inv;
#pragma unroll
    for (int r = 0; r < 4; ++r) inv[r] = 1.f / lp[r];

    const int tq = j * 64 + wave * 16 + lq * 4;
#pragma unroll
    for (int nf = 0; nf < 4; ++nf) {
      const int d   = nf * 16 + l15;
      const int gg  = h * 8 + (d >> 3);
      const int pos = d & 7;
#pragma unroll
      for (int r = 0; r < 4; ++r) {
        const int m = b * TSEQ + tq + r;
        Obf[((size_t)(m >> 7) * KGTOT + gg) * 1024 + (size_t)(m & 127) * 8 + pos] =
            f2bf(o[nf][r] * inv[r]);
      }
    }
  }
}

// ---------- launch ----------

extern "C" void kernel_launch(void* const* d_in, const int* in_sizes, int n_in,
                              void* d_out, int out_size, void* d_ws, size_t ws_size,
                              hipStream_t stream) {
  const float* X     = (const float*)d_in[0];   // (128,256,384)
  const float* Wqkv  = (const float*)d_in[1];   // (384,1152)
  const float* Wproj = (const float*)d_in[2];   // (384,384)
  float* out = (float*)d_out;

  // ws layout (bytes):
  //   KQV bf16: K[768][8][256][8] | Q same | V [768][32][64][8] : 75,497,472
  //   Obf (attn output, tiled A layout for proj)                : 25,165,824
  //   WqkvT bf16 tiled                                          :    884,736
  //   WprojT bf16 tiled                                         :    294,912
  unsigned short* KQV    = (unsigned short*)d_ws;
  unsigned short* Obf    = (unsigned short*)((char*)d_ws + 75497472);
  unsigned short* WqkvT  = (unsigned short*)((char*)d_ws + 75497472 + 25165824);
  unsigned short* WprojT = (unsigned short*)((char*)d_ws + 75497472 + 25165824 + 884736);

  dim3 blk(256);
  convert_w<<<dim3(WBLOCKS), blk, 0, stream>>>(Wqkv, Wproj, WqkvT, WprojT);
  gemm_qkv<<<dim3(2304), blk, 0, stream>>>(X, WqkvT, KQV);
  attn_mfma<<<dim3(NBH), blk, 0, stream>>>(KQV, Obf);
  gemm_proj<<<dim3(768), blk, 0, stream>>>(Obf, WprojT, out, NEMBD);
}

// Round 8
// 173.595 us; speedup vs baseline: 1.0878x; 1.0838x over previous
//
#include <hip/hip_runtime.h>
#include <hip/hip_bf16.h>

#define BATCH 128
#define TSEQ  256
#define NEMBD 384
#define NHEAD 6
#define HDIM  64
#define C3    1152
#define MROWS 32768      // BATCH*TSEQ
#define KGTOT 48         // NEMBD/8
#define NBH   768        // BATCH*NHEAD
#define BHSZ  16384      // TSEQ*HDIM (ushorts per bh per tensor)

#define NA_CH  (MROWS * KGTOT)   // 1572864 chunks (X)
#define NW1_CH (C3 * KGTOT)      // 55296 (Wqkv)
#define NW2_CH (NEMBD * KGTOT)   // 18432 (Wproj)

#define XBLOCKS 2048             // MROWS/16 row-blocks for X convert
#define WBLOCKS 288              // (NW1_CH+NW2_CH)/256 weight-convert blocks

typedef __attribute__((ext_vector_type(8))) short short8v;
typedef __attribute__((ext_vector_type(4))) float float4v;

// ---------- helpers ----------

__device__ __forceinline__ unsigned short f2bf(float f) {
  __hip_bfloat16 h = __float2bfloat16(f);   // RNE
  unsigned short u;
  __builtin_memcpy(&u, &h, 2);
  return u;
}

// ---------- fused converts (R3 structure: gload_lds GEMM needs bf16 Abf) ----------
// X path: 16 rows/block LDS transpose, coalesced both sides.
// W path: per-chunk gather (coalesced in n, tiny).
__device__ __forceinline__ void convB_body(const float* __restrict__ W,
                                           unsigned short* __restrict__ out,
                                           int N, int idx) {
  const int nl  = idx & 127;
  const int kgg = (idx >> 7) % KGTOT;
  const int nb  = idx / (128 * KGTOT);
  const int n = nb * 128 + nl;
  short8v v;
#pragma unroll
  for (int j = 0; j < 8; ++j)
    v[j] = (short)f2bf(W[(size_t)(kgg * 8 + j) * N + n]);
  *reinterpret_cast<short8v*>(out + (size_t)idx * 8) = v;
}

__global__ __launch_bounds__(256)
void convert_all(const float* __restrict__ X, const float* __restrict__ W1,
                 const float* __restrict__ W2, unsigned short* __restrict__ Abf,
                 unsigned short* __restrict__ W1T, unsigned short* __restrict__ W2T) {
  const int tid = threadIdx.x;
  if (blockIdx.x < XBLOCKS) {
    __shared__ __attribute__((aligned(16))) unsigned short T[16][392];  // pad 384->392
    const int rb = blockIdx.x;
    const float* Xb = X + (size_t)rb * 16 * NEMBD;
#pragma unroll
    for (int i = 0; i < 6; ++i) {
      const int f4 = i * 256 + tid;          // float4 index 0..1535
      const float4 v = reinterpret_cast<const float4*>(Xb)[f4];
      const int r = f4 / 96;                 // 96 float4 per row
      const int c = (f4 % 96) * 4;
      ushort4 u;
      u.x = f2bf(v.x); u.y = f2bf(v.y); u.z = f2bf(v.z); u.w = f2bf(v.w);
      *reinterpret_cast<ushort4*>(&T[r][c]) = u;
    }
    __syncthreads();
#pragma unroll
    for (int i = 0; i < 3; ++i) {
      const int c2   = i * 256 + tid;        // chunk 0..767 = [kgg 48][ml16 16]
      const int kgg  = c2 >> 4;
      const int ml16 = c2 & 15;
      const short8v v = *reinterpret_cast<const short8v*>(&T[ml16][kgg * 8]);
      const int m  = rb * 16 + ml16;
      const int mb = m >> 7;
      const int ml = m & 127;
      *reinterpret_cast<short8v*>(Abf + ((size_t)(mb * KGTOT + kgg) * 128 + ml) * 8) = v;
    }
  } else {
    const int wi = (blockIdx.x - XBLOCKS) * 256 + tid;
    if (wi < NW1_CH) convB_body(W1, W1T, C3, wi);
    else             convB_body(W2, W2T, NEMBD, wi - NW1_CH);
  }
}

// ---------- GEMM core: BK=32, ping-pong double-buffered gload_lds staging ----------
// (proven R3 structure: fused reg-staging variants regressed in R5/R6 — T14
// is net-negative vs global_load_lds on GEMM)

#define GEMM_STAGE(Ab, Bb, kb, ASL, BSL)                                               \
  _Pragma("unroll") for (int r = 0; r < 2; ++r) {                                      \
    const int i = r * 256 + tid;                                                       \
    const size_t goff = ((size_t)((kb) * 4 + (i >> 7)) * 128 + (i & 127)) * 8;         \
    __builtin_amdgcn_global_load_lds(                                                  \
        (const __attribute__((address_space(1))) unsigned int*)((Ab) + goff),          \
        (__attribute__((address_space(3))) unsigned int*)((ASL) + i * 8), 16, 0, 0);   \
    __builtin_amdgcn_global_load_lds(                                                  \
        (const __attribute__((address_space(1))) unsigned int*)((Bb) + goff),          \
        (__attribute__((address_space(3))) unsigned int*)((BSL) + i * 8), 16, 0, 0);   \
  }

#define GEMM_CORE(Ab, Bb)                                                              \
  __shared__ __attribute__((aligned(16))) unsigned short S[16384];                     \
  const int tid  = threadIdx.x;                                                        \
  const int wave = tid >> 6;                                                           \
  const int lane = tid & 63;                                                           \
  const int wm  = (wave & 1) * 64;                                                     \
  const int wn  = (wave >> 1) * 64;                                                    \
  const int l15 = lane & 15;                                                           \
  const int lq  = lane >> 4;                                                           \
  float4v acc[4][4];                                                                   \
  _Pragma("unroll") for (int i = 0; i < 4; ++i)                                        \
    _Pragma("unroll") for (int j = 0; j < 4; ++j)                                      \
      acc[i][j] = (float4v){0.f, 0.f, 0.f, 0.f};                                       \
  GEMM_STAGE(Ab, Bb, 0, S, S + 4096)                                                   \
  for (int kb = 0; kb < KGTOT / 4; ++kb) {                                             \
    const int cur = (kb & 1) * 8192;                                                   \
    const int nxt = 8192 - cur;                                                        \
    __syncthreads();                                                                   \
    if (kb + 1 < KGTOT / 4) {                                                          \
      GEMM_STAGE(Ab, Bb, kb + 1, S + nxt, S + nxt + 4096)                              \
    }                                                                                  \
    short8v af[4], bfr[4];                                                             \
    _Pragma("unroll") for (int mi = 0; mi < 4; ++mi)                                   \
      af[mi] = *reinterpret_cast<const short8v*>(                                      \
          S + cur + (size_t)(lq * 128 + wm + mi * 16 + l15) * 8);                      \
    _Pragma("unroll") for (int ni = 0; ni < 4; ++ni)                                   \
      bfr[ni] = *reinterpret_cast<const short8v*>(                                     \
          S + cur + 4096 + (size_t)(lq * 128 + wn + ni * 16 + l15) * 8);               \
    _Pragma("unroll") for (int mi = 0; mi < 4; ++mi)                                   \
      _Pragma("unroll") for (int ni = 0; ni < 4; ++ni)                                 \
        acc[mi][ni] = __builtin_amdgcn_mfma_f32_16x16x32_bf16(af[mi], bfr[ni],         \
                                                              acc[mi][ni], 0, 0, 0);   \
  }

// ---------- QKV GEMM ----------
// Grid 2304, XCD-swizzled (each XCD owns 32 consecutive mtiles, ntile-outer).
// Epilogues:
//   K,Q: LDS-bounce with chunk-XOR swizzle (c ^= ((c>>7)^(c>>3))&7) — cuts the
//        8-way write conflict (row%8,dl-only banks) to ~2-4-way; read side
//        applies the same involution and stays conflict-free.
//   V  : LDS-bounce [hh 2][tg 16][d 64][tl 8] (32 KB) -> 8 coalesced 16B
//        stores/thread, replacing 8B-granular scatter (write-allocate RMW).
__global__ __launch_bounds__(256)
void gemm_qkv(const unsigned short* __restrict__ A,
              const unsigned short* __restrict__ B,
              unsigned short* __restrict__ KQV) {
  const int ord   = blockIdx.x;
  const int xcd   = ord & 7;
  const int g     = ord >> 3;
  const int mtile = xcd * 32 + (g & 31);
  const int ntile = g >> 5;                 // 0..8; 0-2=K, 3-5=Q, 6-8=V
  const unsigned short* Ab = A + (size_t)mtile * (KGTOT * 128 * 8);
  const unsigned short* Bb = B + (size_t)ntile * (KGTOT * 128 * 8);
  GEMM_CORE(Ab, Bb)
  // C/D layout: col = lane&15, row = (lane>>4)*4 + reg
  if (ntile >= 6) {
    unsigned short* Vb = KQV + (size_t)(2 * NBH) * BHSZ;
    const int hh0 = (ntile - 6) * 2;
    const int bb  = mtile >> 1;
    const int tg0 = (mtile & 1) * 16;
    __syncthreads();                                // K-loop done; S reusable
#pragma unroll
    for (int ni = 0; ni < 4; ++ni) {
      const int lc = wn + ni * 16 + l15;            // local col 0..127
      const int hh = lc >> 6;
      const int d  = lc & 63;
#pragma unroll
      for (int mi = 0; mi < 4; ++mi) {
        const int ttl = wm + mi * 16 + lq * 4;      // local row base (%4==0)
        const int tg  = ttl >> 3;
        const int tl0 = ttl & 7;                    // 0 or 4
        ushort4 u;
        u.x = f2bf(acc[mi][ni][0]); u.y = f2bf(acc[mi][ni][1]);
        u.z = f2bf(acc[mi][ni][2]); u.w = f2bf(acc[mi][ni][3]);
        *reinterpret_cast<ushort4*>(
            S + (size_t)(((hh * 16 + tg) * 64 + d) * 8 + tl0)) = u;
      }
    }
    __syncthreads();
#pragma unroll
    for (int it = 0; it < 8; ++it) {
      const int f  = it * 2048 + tid * 8;
      const int cc = f >> 3;
      const int d  = cc & 63;
      const int tg = (cc >> 6) & 15;
      const int hh = cc >> 10;
      *reinterpret_cast<short8v*>(
          Vb + (size_t)(bb * NHEAD + hh0 + hh) * BHSZ + (tg0 + tg) * 512 + d * 8) =
          *reinterpret_cast<const short8v*>(S + f);
    }
  } else {
    const int type = (ntile >= 3) ? 1 : 0;          // 0=K, 1=Q
    const float sc = type ? 0.051031036307982884f : 1.0f;
    unsigned short* outb = KQV + (size_t)type * NBH * BHSZ;
    const int hp = ntile - type * 3;                // head-pair 0..2
    const int bb = mtile >> 1;                      // batch index
    const int t0 = (mtile & 1) * 128;               // t-offset of this mtile
    __syncthreads();                                // K-loop done; S reusable
#pragma unroll
    for (int ni = 0; ni < 4; ++ni) {
      const int lc = wn + ni * 16 + l15;            // local col 0..127
      const int c8 = lc >> 3;
      const int dl = lc & 7;
#pragma unroll
      for (int mi = 0; mi < 4; ++mi) {
        const int lr0 = wm + lq * 4 + mi * 16;
#pragma unroll
        for (int r = 0; r < 4; ++r) {
          const int c  = c8 * 128 + lr0 + r;
          const int cs = c ^ (((c >> 7) ^ (c >> 3)) & 7);
          S[(size_t)cs * 8 + dl] = f2bf(acc[mi][ni][r] * sc);
        }
      }
    }
    __syncthreads();
#pragma unroll
    for (int it = 0; it < 8; ++it) {
      const int f   = it * 2048 + tid * 8;
      const int cc  = f >> 3;
      const int cs  = cc ^ (((cc >> 7) ^ (cc >> 3)) & 7);
      const int c8  = cc >> 7;
      const int lr  = cc & 127;
      const int hh  = hp * 2 + (c8 >> 3);
      const int dg  = c8 & 7;
      *reinterpret_cast<short8v*>(
          outb + (size_t)(bb * NHEAD + hh) * BHSZ + dg * 2048 + (size_t)(t0 + lr) * 8) =
          *reinterpret_cast<const short8v*>(S + (size_t)cs * 8);
    }
  }
}

// ---------- proj GEMM: fp32 output, row-major; LDS-bounce epilogue ----------
__global__ __launch_bounds__(256)
void gemm_proj(const unsigned short* __restrict__ A,
               const unsigned short* __restrict__ B,
               float* __restrict__ C, int N) {
  const int ord   = blockIdx.x;
  const int xcd   = ord & 7;
  const int g     = ord >> 3;
  const int mtile = xcd * 32 + (g & 31);
  const int ntile = g >> 5;                 // 0..2
  const unsigned short* Ab = A + (size_t)mtile * (KGTOT * 128 * 8);
  const unsigned short* Bb = B + (size_t)ntile * (KGTOT * 128 * 8);
  GEMM_CORE(Ab, Bb)
  float* Sf = reinterpret_cast<float*>(S);  // 8192 floats
#pragma unroll
  for (int pass = 0; pass < 2; ++pass) {
    __syncthreads();                        // S free (K-loop done / pass0 read)
    if ((wave & 1) == pass) {               // waves with wm == pass*64
#pragma unroll
      for (int mi = 0; mi < 4; ++mi)
#pragma unroll
        for (int ni = 0; ni < 4; ++ni)
#pragma unroll
          for (int r = 0; r < 4; ++r)
            Sf[(lq * 4 + mi * 16 + r) * 128 + (wn + ni * 16 + l15)] = acc[mi][ni][r];
    }
    __syncthreads();
    const int rowstart = mtile * 128 + pass * 64;
#pragma unroll
    for (int it = 0; it < 8; ++it) {
      const int f  = it * 1024 + tid * 4;
      const int lr = f >> 7;
      const int lc = f & 127;
      *reinterpret_cast<float4*>(&C[(size_t)(rowstart + lr) * N + ntile * 128 + lc]) =
          *reinterpret_cast<const float4*>(&Sf[f]);
    }
  }
}

// ---------- MFMA flash attention, one block per bh ----------
// O-epilogue bounces through the per-wave Pw slot (free after last PV,
// wave-local -> no barrier): 2 coalesced 16B stores/lane replace 128 scalar
// 2B global stores/thread. Pack chunk index XOR-swizzled (^ggl) to cut LDS
// write conflicts; copy loop applies the same involution.
__global__ __launch_bounds__(256, 3)
void attn_mfma(const unsigned short* __restrict__ KQV,
               unsigned short* __restrict__ Obf) {
  const int bh   = blockIdx.x;
  const int b    = bh / NHEAD;
  const int h    = bh - b * NHEAD;
  const int tid  = threadIdx.x;
  const int wave = tid >> 6;
  const int lane = tid & 63;
  const int l15  = lane & 15;
  const int lq   = lane >> 4;

  __shared__ __attribute__((aligned(16))) unsigned short Kls[16384];   // [dg 8][t 256][8]
  __shared__ __attribute__((aligned(16))) unsigned short Pt[4][1024];  // per-wave [kg 8][q 16][8]

  const unsigned short* Kb = KQV + (size_t)bh * BHSZ;
  const unsigned short* Qb = KQV + (size_t)(NBH + bh) * BHSZ;
  const unsigned short* Vb = KQV + (size_t)(2 * NBH + bh) * BHSZ;

#pragma unroll
  for (int r = 0; r < 8; ++r) {
    const int i = r * 256 + tid;
    __builtin_amdgcn_global_load_lds(
        (const __attribute__((address_space(1))) unsigned int*)(Kb + (size_t)i * 8),
        (__attribute__((address_space(3))) unsigned int*)(Kls + i * 8), 16, 0, 0);
  }
  __syncthreads();   // only barrier in the kernel

  unsigned short* Pw = Pt[wave];

  for (int j = 0; j < 4; ++j) {
    short8v qa[2];
#pragma unroll
    for (int s = 0; s < 2; ++s)
      qa[s] = *reinterpret_cast<const short8v*>(
          Qb + (size_t)(s * 4 + lq) * 2048 + (size_t)(j * 64 + wave * 16 + l15) * 8);

    float4v o[4];
#pragma unroll
    for (int nf = 0; nf < 4; ++nf) o[nf] = (float4v){0.f, 0.f, 0.f, 0.f};
    float4v lp = (float4v){0.f, 0.f, 0.f, 0.f};

    for (int kt = 0; kt <= j; ++kt) {
      short8v vf[2][4];
#pragma unroll
      for (int s = 0; s < 2; ++s)
#pragma unroll
        for (int nf = 0; nf < 4; ++nf)
          vf[s][nf] = *reinterpret_cast<const short8v*>(
              Vb + (size_t)(kt * 8 + s * 4 + lq) * 512 + (size_t)(nf * 16 + l15) * 8);

      float4v sf[4];
#pragma unroll
      for (int nf = 0; nf < 4; ++nf) sf[nf] = (float4v){0.f, 0.f, 0.f, 0.f};
#pragma unroll
      for (int s = 0; s < 2; ++s) {
        short8v kf[4];
#pragma unroll
        for (int nf = 0; nf < 4; ++nf)
          kf[nf] = *reinterpret_cast<const short8v*>(
              Kls + (size_t)(s * 4 + lq) * 2048 + (size_t)(kt * 64 + nf * 16 + l15) * 8);
#pragma unroll
        for (int nf = 0; nf < 4; ++nf)
          sf[nf] = __builtin_amdgcn_mfma_f32_16x16x32_bf16(qa[s], kf[nf], sf[nf], 0, 0, 0);
      }

      if (kt == j) {
        const int qit = wave * 16 + lq * 4;
#pragma unroll
        for (int nf = 0; nf < 4; ++nf) {
          const int key = nf * 16 + l15;
#pragma unroll
          for (int r = 0; r < 4; ++r)
            if (key > qit + r) sf[nf][r] = -INFINITY;
        }
      }

#pragma unroll
      for (int nf = 0; nf < 4; ++nf) {
        const int kg  = nf * 2 + (l15 >> 3);
        const int pos = l15 & 7;
#pragma unroll
        for (int r = 0; r < 4; ++r) {
          const float p = __expf(sf[nf][r]);
          lp[r] += p;
          Pw[(kg * 16 + lq * 4 + r) * 8 + pos] = f2bf(p);
        }
      }

#pragma unroll
      for (int s = 0; s < 2; ++s) {
        short8v pa = *reinterpret_cast<const short8v*>(
            Pw + (size_t)((s * 4 + lq) * 16 + l15) * 8);
#pragma unroll
        for (int nf = 0; nf < 4; ++nf)
          o[nf] = __builtin_amdgcn_mfma_f32_16x16x32_bf16(pa, vf[s][nf], o[nf], 0, 0, 0);
      }
    }

#pragma unroll
    for (int off = 1; off <= 8; off <<= 1)
#pragma unroll
      for (int r = 0; r < 4; ++r)
        lp[r] += __shfl_xor(lp[r], off);
    float4v inv;
#pragma unroll
    for (int r = 0; r < 4; ++r) inv[r] = 1.f / lp[r];

    // pack normalized O into Pw: [ggl 8][mll 16][pos 8], chunk ^ ggl swizzle
#pragma unroll
    for (int nf = 0; nf < 4; ++nf) {
      const int d   = nf * 16 + l15;
      const int ggl = d >> 3;
      const int pos = d & 7;
#pragma unroll
      for (int r = 0; r < 4; ++r) {
        const int chunk = (ggl * 16 + lq * 4 + r) ^ ggl;
        Pw[chunk * 8 + pos] = f2bf(o[nf][r] * inv[r]);
      }
    }
    const int mb  = b * 2 + (j >> 1);
    const int ml0 = (j & 1) * 64 + wave * 16;
#pragma unroll
    for (int t = 0; t < 2; ++t) {
      const int cc  = t * 64 + lane;
      const int ggl = cc >> 4;
      const int mll = cc & 15;
      *reinterpret_cast<short8v*>(
          Obf + ((size_t)(mb * KGTOT) + h * 8 + ggl) * 1024 + (size_t)(ml0 + mll) * 8) =
          *reinterpret_cast<const short8v*>(Pw + (size_t)(cc ^ ggl) * 8);
    }
  }
}

// ---------- launch ----------

extern "C" void kernel_launch(void* const* d_in, const int* in_sizes, int n_in,
                              void* d_out, int out_size, void* d_ws, size_t ws_size,
                              hipStream_t stream) {
  const float* X     = (const float*)d_in[0];   // (128,256,384)
  const float* Wqkv  = (const float*)d_in[1];   // (384,1152)
  const float* Wproj = (const float*)d_in[2];   // (384,384)
  float* out = (float*)d_out;

  // ws layout (bytes):
  //   KQV bf16: K[768][8][256][8] | Q same | V [768][32][64][8] : 75,497,472
  //   Abf (X bf16 tiled) -> reused as Obf                       : 25,165,824
  //   WqkvT bf16 tiled                                          :    884,736
  //   WprojT bf16 tiled                                         :    294,912
  unsigned short* KQV    = (unsigned short*)d_ws;
  unsigned short* Abf    = (unsigned short*)((char*)d_ws + 75497472);
  unsigned short* WqkvT  = (unsigned short*)((char*)d_ws + 75497472 + 25165824);
  unsigned short* WprojT = (unsigned short*)((char*)d_ws + 75497472 + 25165824 + 884736);
  unsigned short* Obf    = Abf;   // alias: Abf fully consumed before attn writes

  dim3 blk(256);
  convert_all<<<dim3(XBLOCKS + WBLOCKS), blk, 0, stream>>>(
      X, Wqkv, Wproj, Abf, WqkvT, WprojT);
  gemm_qkv<<<dim3(2304), blk, 0, stream>>>(Abf, WqkvT, KQV);
  attn_mfma<<<dim3(NBH), blk, 0, stream>>>(KQV, Obf);
  gemm_proj<<<dim3(768), blk, 0, stream>>>(Obf, WprojT, out, NEMBD);
}